// Round 8
// baseline (1191.772 us; speedup 1.0000x reference)
//
#include <hip/hip_runtime.h>
#include <hip/hip_bf16.h>

typedef unsigned short u16;
typedef unsigned int u32;

static __device__ __forceinline__ float us2f(u16 u) {
    return __uint_as_float(((u32)u) << 16);
}
static __device__ __forceinline__ u16 f2bu(float f) {  // RNE
    u32 u = __float_as_uint(f);
    return (u16)((u + 0x7fffu + ((u >> 16) & 1u)) >> 16);
}

typedef __attribute__((ext_vector_type(8))) __bf16 bf16x8;
typedef __attribute__((ext_vector_type(4))) float f32x4;

__global__ void fill_sentinel(float* out, int n, float val) {
    int g = blockIdx.x * 256 + threadIdx.x;
    if (g < n) out[g] = val;
}

// ============================================================
// Kernel 1: conv1 9x9 s1 + bias + relu -> h NHWC bf16 [B][20][20][256]
// grid B*4, block 256 (=channel). wl pad 258 (bank-clean scatter).
// ============================================================
__global__ __launch_bounds__(256) void conv1_kernel(const float* __restrict__ x,
    const float* __restrict__ w, const float* __restrict__ bias, u16* __restrict__ h)
{
    __shared__ float xs[784];
    __shared__ u16 wl[81 * 258];   // [tap][channel] bf16, pad 258
    const int b = blockIdx.x >> 2, g = blockIdx.x & 3;
    const int c = threadIdx.x;
    for (int idx = c; idx < 784; idx += 256) xs[idx] = x[b * 784 + idx];
    for (int idx = c; idx < 20736; idx += 256) {      // coalesced read, clean scatter
        const int cc = idx / 81, jj = idx - cc * 81;
        wl[jj * 258 + cc] = f2bu(w[idx]);
    }
    __syncthreads();
    const float bv = bias[c];
    #pragma unroll 1
    for (int iy = g * 5; iy < g * 5 + 5; ++iy) {
        float acc[20];
        #pragma unroll
        for (int i = 0; i < 20; ++i) acc[i] = bv;
        #pragma unroll 1
        for (int dy = 0; dy < 9; ++dy) {
            float xr[28];
            const float4* xrow = reinterpret_cast<const float4*>(&xs[(iy + dy) * 28]);
            #pragma unroll
            for (int i = 0; i < 7; ++i) {
                float4 v = xrow[i];
                xr[4*i] = v.x; xr[4*i+1] = v.y; xr[4*i+2] = v.z; xr[4*i+3] = v.w;
            }
            #pragma unroll
            for (int dx = 0; dx < 9; ++dx) {
                const float wv = us2f(wl[(dy * 9 + dx) * 258 + c]);
                #pragma unroll
                for (int ix = 0; ix < 20; ++ix) acc[ix] += xr[ix + dx] * wv;
            }
        }
        u16* hp = h + ((b * 20 + iy) * 20) * 256 + c;
        #pragma unroll
        for (int ix = 0; ix < 20; ++ix) hp[ix * 256] = f2bu(fmaxf(acc[ix], 0.f));
    }
}

// ============================================================
// Kernel 2: transpose prim_w f32 [n][c][kyx] -> wT2 bf16 [n][kyx][c]
// grid 256 (=n), block 256; pad-258 LDS bounce (bank-clean both sides)
// ============================================================
__global__ __launch_bounds__(256) void transpose_primw(const float* __restrict__ w,
                                                       u16* __restrict__ wt)
{
    __shared__ u16 wl[81 * 258];
    const int n = blockIdx.x, tid = threadIdx.x;
    const float* ws = w + (size_t)n * 20736;
    for (int idx = tid; idx < 20736; idx += 256) {
        const int cc = idx / 81, kk = idx - cc * 81;
        wl[kk * 258 + cc] = f2bu(ws[idx]);
    }
    __syncthreads();
    u16* wo = wt + (size_t)n * 20736;
    for (int q = tid; q < 20736; q += 256)
        wo[q] = wl[(q >> 8) * 258 + (q & 255)];
}

// ============================================================
// Kernel 3: dw f32 -> bf16 (digit_w, read 5x per routing at half width)
// ============================================================
__global__ __launch_bounds__(256) void conv_dwb(const float* __restrict__ dw,
                                                u16* __restrict__ dwb)
{
    const int g = blockIdx.x * 256 + threadIdx.x;   // 1,474,560
    dwb[g] = f2bu(dw[g]);
}

// ============================================================
// Kernel 4: primary-caps implicit GEMM, MFMA bf16 16x16x32.
// split-K=9 (one ky row each: 2304), BK=64, 128x128 tile, pad 72 u16.
// grid (144, 9), block 256 (4 waves 2x2). f32 atomics into pm (zeroed).
// ============================================================
__global__ __launch_bounds__(256) void prim_gemm_split(const u16* __restrict__ h,
    const u16* __restrict__ wT, float* __restrict__ pm)
{
    __shared__ u16 As[128 * 72];
    __shared__ u16 Bs[128 * 72];
    const int tid = threadIdx.x;
    const int split = blockIdx.y;                 // == ky
    const int mt = blockIdx.x % 72, nt = blockIdx.x / 72;
    const int mBase = mt * 128, nBase = nt * 128;
    const int tq = tid & 7, tr = tid >> 3;        // k-chunk(8 u16), row(0..31)
    int aB[4], bB[4];
    #pragma unroll
    for (int j = 0; j < 4; ++j) {
        const int m = mBase + tr + j * 32;
        const int bb = m / 36, r = m % 36;
        aB[j] = ((bb * 20 + 2 * (r / 6)) * 20 + 2 * (r % 6)) * 256 + tq * 8;
        bB[j] = (nBase + tr + j * 32) * 20736 + split * 2304 + tq * 8;
    }

    f32x4 acc[4][4];
    #pragma unroll
    for (int i = 0; i < 4; ++i)
        #pragma unroll
        for (int j = 0; j < 4; ++j) acc[i][j] = (f32x4){0.f, 0.f, 0.f, 0.f};

    const int lane = tid & 63;
    const int wvi = tid >> 6; const int wm = wvi >> 1, wn = wvi & 1;
    const int lcol = lane & 15, lquad = lane >> 4;

    #pragma unroll 1
    for (int kt = 0; kt < 36; ++kt) {
        const int kx = kt >> 2, c0 = (kt & 3) << 6;
        const int koffA = (split * 20 + kx) * 256 + c0;
        const int koffB = kx * 256 + c0;
        uint4 ra[4], rb[4];
        #pragma unroll
        for (int j = 0; j < 4; ++j) {
            ra[j] = *reinterpret_cast<const uint4*>(h + aB[j] + koffA);
            rb[j] = *reinterpret_cast<const uint4*>(wT + bB[j] + koffB);
        }
        __syncthreads();
        #pragma unroll
        for (int j = 0; j < 4; ++j) {
            *reinterpret_cast<uint4*>(As + (tr + j * 32) * 72 + tq * 8) = ra[j];
            *reinterpret_cast<uint4*>(Bs + (tr + j * 32) * 72 + tq * 8) = rb[j];
        }
        __syncthreads();
        #pragma unroll
        for (int hh = 0; hh < 2; ++hh) {
            bf16x8 af[4], bf[4];
            #pragma unroll
            for (int i = 0; i < 4; ++i)
                af[i] = *reinterpret_cast<const bf16x8*>(
                    As + (wm * 64 + i * 16 + lcol) * 72 + hh * 32 + lquad * 8);
            #pragma unroll
            for (int j = 0; j < 4; ++j)
                bf[j] = *reinterpret_cast<const bf16x8*>(
                    Bs + (wn * 64 + j * 16 + lcol) * 72 + hh * 32 + lquad * 8);
            #pragma unroll
            for (int i = 0; i < 4; ++i)
                #pragma unroll
                for (int j = 0; j < 4; ++j)
                    acc[i][j] = __builtin_amdgcn_mfma_f32_16x16x32_bf16(af[i], bf[j], acc[i][j], 0, 0, 0);
        }
    }
    #pragma unroll
    for (int i = 0; i < 4; ++i) {
        const int mrow = mBase + wm * 64 + i * 16 + lquad * 4;
        #pragma unroll
        for (int j = 0; j < 4; ++j) {
            const int ncol = nBase + wn * 64 + j * 16 + lcol;
            #pragma unroll
            for (int r = 0; r < 4; ++r)
                unsafeAtomicAdd(&pm[(size_t)(mrow + r) * 256 + ncol], acc[i][j][r]);
        }
    }
}

// ============================================================
// Kernel 5: in-place /32 + prim_b + squash over 8-atom groups (row-local)
// ============================================================
__global__ __launch_bounds__(256) void squash_kernel(float* __restrict__ pm,
    const float* __restrict__ pb)
{
    const int m = blockIdx.x, t = threadIdx.x;
    float pre = pm[(size_t)m * 256 + t] * (1.f / 32.f) + pb[t];
    float sq = pre * pre;
    sq += __shfl_xor(sq, 1); sq += __shfl_xor(sq, 2); sq += __shfl_xor(sq, 4);
    float scale = (sq / (1.f + sq)) * rsqrtf(sq + 1e-9f);
    pm[(size_t)m * 256 + t] = pre * scale;
}

// ============================================================
// Kernel 6: routing preact partial (dw in bf16). grid (9, 32), block 256.
// 8 b's per block; dwb slice read once serves 8 b's. preactD via atomics.
// ============================================================
__global__ __launch_bounds__(256) void routing_act_part(const float* __restrict__ x3m,
    const u16* __restrict__ dwb, const float* __restrict__ logits,
    float* __restrict__ preactD, int uniform)
{
    __shared__ float x3s[8192];    // [b][il][a] 32 KB
    __shared__ float rs[10240];    // [b][il][o] 40 KB
    const int c = blockIdx.x, bg = blockIdx.y;
    const int tid = threadIdx.x;
    for (int q = tid; q < 8192; q += 256) {
        const int b_l = q >> 10, rest = q & 1023, il = rest >> 3, a = rest & 7;
        const int i = c * 128 + il, cap = i / 36, p = i - cap * 36;
        x3s[q] = x3m[((size_t)(bg * 8 + b_l) * 36 + p) * 256 + cap * 8 + a];
    }
    if (!uniform && tid < 128) {
        const int i = c * 128 + tid;
        for (int b_l = 0; b_l < 8; ++b_l) {
            const float* lg = &logits[((size_t)(bg * 8 + b_l) * 1152 + i) * 10];
            float l[10]; float mx = -1e30f;
            #pragma unroll
            for (int k = 0; k < 10; ++k) { l[k] = lg[k]; mx = fmaxf(mx, l[k]); }
            float s = 0.f;
            #pragma unroll
            for (int k = 0; k < 10; ++k) { l[k] = __expf(l[k] - mx); s += l[k]; }
            const float inv = 1.f / s;
            #pragma unroll
            for (int k = 0; k < 10; ++k) rs[(b_l * 128 + tid) * 10 + k] = l[k] * inv;
        }
    }
    __syncthreads();
    if (tid < 160) {
        const int o = tid >> 4, t = tid & 15;
        float preg[8];
        #pragma unroll
        for (int b_l = 0; b_l < 8; ++b_l) preg[b_l] = 0.f;
        #pragma unroll 1
        for (int il = 0; il < 128; ++il) {
            const int i = c * 128 + il;
            float dv[8];
            #pragma unroll
            for (int a = 0; a < 8; ++a)
                dv[a] = us2f(dwb[(((size_t)i * 8 + a) * 10 + o) * 16 + t]);
            #pragma unroll
            for (int b_l = 0; b_l < 8; ++b_l) {
                const float* xp = &x3s[(b_l * 128 + il) * 8];
                float v = 0.f;
                #pragma unroll
                for (int a = 0; a < 8; ++a) v += xp[a] * dv[a];
                const float r = uniform ? 0.1f : rs[(b_l * 128 + il) * 10 + o];
                preg[b_l] += r * v;
            }
        }
        #pragma unroll
        for (int b_l = 0; b_l < 8; ++b_l)
            unsafeAtomicAdd(&preactD[(size_t)(bg * 8 + b_l) * 160 + tid], preg[b_l]);
    }
}

// ============================================================
// Kernel 7: preactD + digit_b -> squash -> act (+digit out)
// ============================================================
__global__ __launch_bounds__(192) void routing_squash(const float* __restrict__ preactD,
    const float* __restrict__ db, float* __restrict__ act, float* __restrict__ dout)
{
    const int b = blockIdx.x, tid = threadIdx.x;
    if (tid < 160) {
        float pre = preactD[(size_t)b * 160 + tid] + db[tid];
        float sq = pre * pre;
        sq += __shfl_xor(sq, 1); sq += __shfl_xor(sq, 2);
        sq += __shfl_xor(sq, 4); sq += __shfl_xor(sq, 8);
        float scale = (sq / (1.f + sq)) * rsqrtf(sq + 1e-9f);
        float a = pre * scale;
        act[(size_t)b * 160 + tid] = a;
        if (dout) dout[(size_t)b * 160 + tid] = a;
    }
}

// ============================================================
// Kernel 8: logits update (dw bf16, uint4-vectorized over t).
// grid (9, 32), block 256 = 128 i x 2 o-halves; 8 b's inside.
// ============================================================
__global__ __launch_bounds__(256) void routing_upd_part(const float* __restrict__ x3m,
    const u16* __restrict__ dwb, const float* __restrict__ act,
    float* __restrict__ logits, int first)
{
    __shared__ float x3s[8192];
    __shared__ float acts[1280];
    const int c = blockIdx.x, bg = blockIdx.y;
    const int tid = threadIdx.x;
    for (int q = tid; q < 8192; q += 256) {
        const int b_l = q >> 10, rest = q & 1023, il = rest >> 3, a = rest & 7;
        const int i = c * 128 + il, cap = i / 36, p = i - cap * 36;
        x3s[q] = x3m[((size_t)(bg * 8 + b_l) * 36 + p) * 256 + cap * 8 + a];
    }
    for (int q = tid; q < 1280; q += 256)
        acts[q] = act[(size_t)(bg * 8 + q / 160) * 160 + (q % 160)];
    __syncthreads();
    const int il = tid >> 1, half = tid & 1;
    const int i = c * 128 + il;
    #pragma unroll 1
    for (int oo = 0; oo < 5; ++oo) {
        const int o = half * 5 + oo;
        float s[8];
        #pragma unroll
        for (int b_l = 0; b_l < 8; ++b_l) s[b_l] = 0.f;
        #pragma unroll
        for (int a = 0; a < 8; ++a) {
            const uint4* dp = reinterpret_cast<const uint4*>(
                &dwb[(((size_t)i * 8 + a) * 10 + o) * 16]);
            uint4 d0 = dp[0], d1 = dp[1];
            const u32 du[8] = {d0.x, d0.y, d0.z, d0.w, d1.x, d1.y, d1.z, d1.w};
            #pragma unroll
            for (int b_l = 0; b_l < 8; ++b_l) {
                const float* ap = &acts[b_l * 160 + o * 16];
                float inner = 0.f;
                #pragma unroll
                for (int q = 0; q < 8; ++q) {
                    inner += __uint_as_float(du[q] << 16) * ap[2 * q];
                    inner += __uint_as_float(du[q] & 0xffff0000u) * ap[2 * q + 1];
                }
                s[b_l] += x3s[(b_l * 128 + il) * 8 + a] * inner;
            }
        }
        #pragma unroll
        for (int b_l = 0; b_l < 8; ++b_l) {
            float* lp = &logits[((size_t)(bg * 8 + b_l) * 1152 + i) * 10 + o];
            if (first) *lp = s[b_l]; else *lp += s[b_l];
        }
    }
}

// ============================================================
// Kernel 9: masked[b][j] = act[b][j] * y[b][j/16]
// ============================================================
__global__ __launch_bounds__(256) void masked_kernel(const float* __restrict__ act,
    const float* __restrict__ y, float* __restrict__ masked)
{
    const int gid = blockIdx.x * 256 + threadIdx.x;  // 40960
    const int b = gid / 160, j = gid % 160;
    masked[gid] = act[gid] * y[b * 10 + (j >> 4)];
}

// ============================================================
// Kernel 10: dense layer; 4 batch rows/block; mode 0=relu, 1=sigmoid
// grid (B/4, ceil(N/256)), block 256
// ============================================================
__global__ __launch_bounds__(256) void mlp_layer(const float* __restrict__ in,
    const float* __restrict__ w, const float* __restrict__ bias,
    float* __restrict__ outp, int K, int N, int mode)
{
    __shared__ float ins[4 * 1024];
    const int b0 = blockIdx.x * 4;
    const int n = blockIdx.y * 256 + threadIdx.x;
    for (int idx = threadIdx.x; idx < 4 * K; idx += 256)
        ins[idx] = in[(size_t)b0 * K + idx];
    __syncthreads();
    if (n < N) {
        float a0 = 0.f, a1 = 0.f, a2 = 0.f, a3 = 0.f;
        for (int k = 0; k < K; ++k) {
            const float wvv = w[(size_t)k * N + n];
            a0 += ins[k] * wvv;
            a1 += ins[K + k] * wvv;
            a2 += ins[2 * K + k] * wvv;
            a3 += ins[3 * K + k] * wvv;
        }
        const float bv = bias[n];
        float v[4] = {a0 + bv, a1 + bv, a2 + bv, a3 + bv};
        #pragma unroll
        for (int j = 0; j < 4; ++j) {
            float xv = v[j];
            xv = (mode == 0) ? fmaxf(xv, 0.f) : 1.f / (1.f + __expf(-xv));
            outp[(size_t)(b0 + j) * N + n] = xv;
        }
    }
}

// ============================================================
extern "C" void kernel_launch(void* const* d_in, const int* in_sizes, int n_in,
                              void* d_out, int out_size, void* d_ws, size_t ws_size,
                              hipStream_t stream) {
    const float* x   = (const float*)d_in[0];
    const float* y   = (const float*)d_in[1];
    const float* c1w = (const float*)d_in[2];
    const float* c1b = (const float*)d_in[3];
    const float* pw  = (const float*)d_in[4];
    const float* pb  = (const float*)d_in[5];
    const float* dw  = (const float*)d_in[6];
    const float* db  = (const float*)d_in[7];
    const float* w1  = (const float*)d_in[8];
    const float* b1  = (const float*)d_in[9];
    const float* w2  = (const float*)d_in[10];
    const float* b2  = (const float*)d_in[11];
    const float* w3  = (const float*)d_in[12];
    const float* b3  = (const float*)d_in[13];
    float* out = (float*)d_out;
    char* ws = (char*)d_ws;

    static const int exp_sizes[14] = {200704, 2560, 20736, 256, 5308416, 256,
                                      1474560, 160, 81920, 512, 524288, 1024,
                                      802816, 784};
    int bad = (n_in == 14) ? -1 : -2;
    if (bad == -1)
        for (int i = 0; i < 14; ++i) if (in_sizes[i] != exp_sizes[i]) { bad = i; break; }
    if (bad != -1) {
        fill_sentinel<<<(out_size + 255) / 256, 256, 0, stream>>>(out, out_size,
            7168.f + 16.f * (float)(bad + 1));
        return;
    }
    const size_t NEEDED = 72482816ULL;
    if (ws_size < NEEDED) {
        fill_sentinel<<<(out_size + 255) / 256, 256, 0, stream>>>(out, out_size, 111.0f);
        return;
    }

    // GEMM-phase live set: h + wT2 + x3m = 72.5 MB
    u16*   h       = (u16*)(ws);                    // [0, 52,428,800)
    u16*   wT2     = (u16*)(ws + 52428800);         // [52,428,800, 63,045,632)
    float* x3m     = (float*)(ws + 63045632);       // [63,045,632, 72,482,816)
    // after GEMM, h/wT2 dead: routing/recon overlays
    float* logits  = (float*)(ws);                  // 11,796,480
    float* act     = (float*)(ws + 11796480);       //    163,840
    float* masked  = (float*)(ws + 11960320);       //    163,840
    float* r1      = (float*)(ws + 12124160);       //    524,288
    float* r2      = (float*)(ws + 12648448);       //  1,048,576
    float* preactD = (float*)(ws + 13697024);       //    163,840
    u16*   dwb     = (u16*)(ws + 13860864);         //  2,949,120 (built post-GEMM)

    conv1_kernel<<<1024, 256, 0, stream>>>(x, c1w, c1b, h);
    transpose_primw<<<256, 256, 0, stream>>>(pw, wT2);
    hipMemsetAsync(x3m, 0, 9437184, stream);
    prim_gemm_split<<<dim3(144, 9), 256, 0, stream>>>(h, wT2, x3m);
    squash_kernel<<<9216, 256, 0, stream>>>(x3m, pb);
    conv_dwb<<<5760, 256, 0, stream>>>(dw, dwb);

    // routing iter 1 (uniform), 2, 3
    hipMemsetAsync(preactD, 0, 163840, stream);
    routing_act_part<<<dim3(9, 32), 256, 0, stream>>>(x3m, dwb, logits, preactD, 1);
    routing_squash<<<256, 192, 0, stream>>>(preactD, db, act, (float*)nullptr);
    routing_upd_part<<<dim3(9, 32), 256, 0, stream>>>(x3m, dwb, act, logits, 1);

    hipMemsetAsync(preactD, 0, 163840, stream);
    routing_act_part<<<dim3(9, 32), 256, 0, stream>>>(x3m, dwb, logits, preactD, 0);
    routing_squash<<<256, 192, 0, stream>>>(preactD, db, act, (float*)nullptr);
    routing_upd_part<<<dim3(9, 32), 256, 0, stream>>>(x3m, dwb, act, logits, 0);

    hipMemsetAsync(preactD, 0, 163840, stream);
    routing_act_part<<<dim3(9, 32), 256, 0, stream>>>(x3m, dwb, logits, preactD, 0);
    routing_squash<<<256, 192, 0, stream>>>(preactD, db, act, out);

    // reconstruction
    masked_kernel<<<160, 256, 0, stream>>>(act, y, masked);
    mlp_layer<<<dim3(64, 2), 256, 0, stream>>>(masked, w1, b1, r1, 160, 512, 0);
    mlp_layer<<<dim3(64, 4), 256, 0, stream>>>(r1, w2, b2, r2, 512, 1024, 0);
    mlp_layer<<<dim3(64, 4), 256, 0, stream>>>(r2, w3, b3, out + 40960, 1024, 784, 1);
}

// Round 9
// 813.068 us; speedup vs baseline: 1.4658x; 1.4658x over previous
//
#include <hip/hip_runtime.h>
#include <hip/hip_bf16.h>

typedef unsigned short u16;
typedef unsigned int u32;

static __device__ __forceinline__ float us2f(u16 u) {
    return __uint_as_float(((u32)u) << 16);
}
static __device__ __forceinline__ u16 f2bu(float f) {  // RNE
    u32 u = __float_as_uint(f);
    return (u16)((u + 0x7fffu + ((u >> 16) & 1u)) >> 16);
}

typedef __attribute__((ext_vector_type(8))) __bf16 bf16x8;
typedef __attribute__((ext_vector_type(4))) float f32x4;

__global__ void fill_sentinel(float* out, int n, float val) {
    int g = blockIdx.x * 256 + threadIdx.x;
    if (g < n) out[g] = val;
}

// ============================================================
// Kernel 0: conv1 weights f32 [c][j] -> bf16 [j][c] (one-time)
// ============================================================
__global__ __launch_bounds__(256) void conv_c1wb(const float* __restrict__ w,
                                                 u16* __restrict__ wb)
{
    const int j = blockIdx.x, c = threadIdx.x;   // 81 x 256
    wb[j * 256 + c] = f2bu(w[c * 81 + j]);
}

// ============================================================
// Kernel 1: conv1 9x9 s1 + bias + relu -> h NHWC bf16 [B][20][20][256]
// grid B*4, block 256 (=channel). Weight staging = linear coalesced copy.
// ============================================================
__global__ __launch_bounds__(256) void conv1_kernel(const float* __restrict__ x,
    const u16* __restrict__ wb, const float* __restrict__ bias, u16* __restrict__ h)
{
    __shared__ float xs[784];
    __shared__ u16 wl[81 * 256];   // [tap][channel] bf16
    const int b = blockIdx.x >> 2, g = blockIdx.x & 3;
    const int c = threadIdx.x;
    for (int idx = c; idx < 784; idx += 256) xs[idx] = x[b * 784 + idx];
    for (int idx = c; idx < 20736; idx += 256) wl[idx] = wb[idx];
    __syncthreads();
    const float bv = bias[c];
    #pragma unroll 1
    for (int iy = g * 5; iy < g * 5 + 5; ++iy) {
        float acc[20];
        #pragma unroll
        for (int i = 0; i < 20; ++i) acc[i] = bv;
        #pragma unroll 1
        for (int dy = 0; dy < 9; ++dy) {
            float xr[28];
            const float4* xrow = reinterpret_cast<const float4*>(&xs[(iy + dy) * 28]);
            #pragma unroll
            for (int i = 0; i < 7; ++i) {
                float4 v = xrow[i];
                xr[4*i] = v.x; xr[4*i+1] = v.y; xr[4*i+2] = v.z; xr[4*i+3] = v.w;
            }
            #pragma unroll
            for (int dx = 0; dx < 9; ++dx) {
                const float wv = us2f(wl[(dy * 9 + dx) * 256 + c]);
                #pragma unroll
                for (int ix = 0; ix < 20; ++ix) acc[ix] += xr[ix + dx] * wv;
            }
        }
        u16* hp = h + ((b * 20 + iy) * 20) * 256 + c;
        #pragma unroll
        for (int ix = 0; ix < 20; ++ix) hp[ix * 256] = f2bu(fmaxf(acc[ix], 0.f));
    }
}

// ============================================================
// Kernel 2: transpose prim_w f32 [n][c][kyx] -> wT2 bf16 [n][kyx][c]
// grid 256 (=n), block 256; pad-258 LDS bounce
// ============================================================
__global__ __launch_bounds__(256) void transpose_primw(const float* __restrict__ w,
                                                       u16* __restrict__ wt)
{
    __shared__ u16 wl[81 * 258];
    const int n = blockIdx.x, tid = threadIdx.x;
    const float* ws = w + (size_t)n * 20736;
    for (int idx = tid; idx < 20736; idx += 256) {
        const int cc = idx / 81, kk = idx - cc * 81;
        wl[kk * 258 + cc] = f2bu(ws[idx]);
    }
    __syncthreads();
    u16* wo = wt + (size_t)n * 20736;
    for (int q = tid; q < 20736; q += 256)
        wo[q] = wl[(q >> 8) * 258 + (q & 255)];
}

// ============================================================
// Kernel 3: dw f32 -> two bf16 layouts:
//   dwb_t[i][a][o][t]  (same order as src)   for logits-update
//   dwb_a[i][o][t][a]  (a contiguous)        for act recompute
// ============================================================
__global__ __launch_bounds__(256) void conv_dwb(const float* __restrict__ dw,
    u16* __restrict__ dwb_t, u16* __restrict__ dwb_a)
{
    const int g = blockIdx.x * 256 + threadIdx.x;   // 1,474,560
    const float v = dw[g];
    const u16 bv = f2bu(v);
    dwb_t[g] = bv;
    const int i = g / 1280, rem = g % 1280;
    const int a = rem / 160, ot = rem % 160;        // ot = o*16+t
    dwb_a[((size_t)i * 160 + ot) * 8 + a] = bv;
}

// ============================================================
// Kernel 4: primary-caps implicit GEMM, MFMA bf16 16x16x32 (r7 structure).
// split-K=12 (1728 k each), BK=32, 128x128 tile, pad 40 u16.
// grid (144, 12), block 256 (4 waves 2x2). f32 atomics into pm (zeroed).
// ============================================================
__global__ __launch_bounds__(256) void prim_gemm_split(const u16* __restrict__ h,
    const u16* __restrict__ wT, float* __restrict__ pm)
{
    __shared__ u16 As[128 * 40];
    __shared__ u16 Bs[128 * 40];
    const int tid = threadIdx.x;
    const int split = blockIdx.y;
    const int mt = blockIdx.x % 72, nt = blockIdx.x / 72;
    const int mBase = mt * 128, nBase = nt * 128;
    const int tq = tid & 3, tr = tid >> 2;
    int m0 = mBase + tr;
    int b0 = m0 / 36, r0 = m0 % 36;
    int aBase0 = ((b0 * 20 + 2 * (r0 / 6)) * 20 + 2 * (r0 % 6)) * 256 + tq * 8;
    int m1 = m0 + 64;
    int b1 = m1 / 36, r1 = m1 % 36;
    int aBase1 = ((b1 * 20 + 2 * (r1 / 6)) * 20 + 2 * (r1 % 6)) * 256 + tq * 8;
    const int bBase0 = (nBase + tr) * 20736 + tq * 8;
    const int bBase1 = (nBase + tr + 64) * 20736 + tq * 8;
    // split covers k in [split*1728, (split+1)*1728)
    int kglob = split * 1728;
    int ky = kglob / 2304; int krem = kglob - ky * 2304;
    int kx = krem >> 8; int c0 = krem & 255;

    f32x4 acc[4][4];
    #pragma unroll
    for (int i = 0; i < 4; ++i)
        #pragma unroll
        for (int j = 0; j < 4; ++j) acc[i][j] = (f32x4){0.f, 0.f, 0.f, 0.f};

    const int lane = tid & 63;
    const int wvi = tid >> 6; const int wm = wvi >> 1, wn = wvi & 1;
    const int lcol = lane & 15, lquad = lane >> 4;
    const u16* Arow = As + (wm * 64 + lcol) * 40 + lquad * 8;
    const u16* Brow = Bs + (wn * 64 + lcol) * 40 + lquad * 8;

    #pragma unroll 1
    for (int kt = 0; kt < 54; ++kt) {
        const int koffA = (ky * 20 + kx) * 256 + c0;
        uint4 ra0 = *reinterpret_cast<const uint4*>(h + aBase0 + koffA);
        uint4 ra1 = *reinterpret_cast<const uint4*>(h + aBase1 + koffA);
        uint4 rb0 = *reinterpret_cast<const uint4*>(wT + bBase0 + kglob);
        uint4 rb1 = *reinterpret_cast<const uint4*>(wT + bBase1 + kglob);
        __syncthreads();
        *reinterpret_cast<uint4*>(As + tr * 40 + tq * 8)        = ra0;
        *reinterpret_cast<uint4*>(As + (tr + 64) * 40 + tq * 8) = ra1;
        *reinterpret_cast<uint4*>(Bs + tr * 40 + tq * 8)        = rb0;
        *reinterpret_cast<uint4*>(Bs + (tr + 64) * 40 + tq * 8) = rb1;
        __syncthreads();
        bf16x8 af[4], bfr[4];
        #pragma unroll
        for (int i = 0; i < 4; ++i)
            af[i] = *reinterpret_cast<const bf16x8*>(Arow + i * 640);
        #pragma unroll
        for (int j = 0; j < 4; ++j)
            bfr[j] = *reinterpret_cast<const bf16x8*>(Brow + j * 640);
        #pragma unroll
        for (int i = 0; i < 4; ++i)
            #pragma unroll
            for (int j = 0; j < 4; ++j)
                acc[i][j] = __builtin_amdgcn_mfma_f32_16x16x32_bf16(af[i], bfr[j], acc[i][j], 0, 0, 0);
        kglob += 32; c0 += 32;
        if (c0 == 256) { c0 = 0; if (++kx == 9) { kx = 0; ++ky; } }
    }
    #pragma unroll
    for (int i = 0; i < 4; ++i) {
        const int mrow = mBase + wm * 64 + i * 16 + lquad * 4;
        #pragma unroll
        for (int j = 0; j < 4; ++j) {
            const int ncol = nBase + wn * 64 + j * 16 + lcol;
            #pragma unroll
            for (int r = 0; r < 4; ++r)
                unsafeAtomicAdd(&pm[(size_t)(mrow + r) * 256 + ncol], acc[i][j][r]);
        }
    }
}

// ============================================================
// Kernel 5: in-place /32 + prim_b + squash over 8-atom groups (row-local)
// ============================================================
__global__ __launch_bounds__(256) void squash_kernel(float* __restrict__ pm,
    const float* __restrict__ pb)
{
    const int m = blockIdx.x, t = threadIdx.x;
    float pre = pm[(size_t)m * 256 + t] * (1.f / 32.f) + pb[t];
    float sq = pre * pre;
    sq += __shfl_xor(sq, 1); sq += __shfl_xor(sq, 2); sq += __shfl_xor(sq, 4);
    float scale = (sq / (1.f + sq)) * rsqrtf(sq + 1e-9f);
    pm[(size_t)m * 256 + t] = pre * scale;
}

// ============================================================
// Kernel 6: routing preact partial (dwb_a [i][o][t][a]). grid (9, 32), block 256.
// 8 b's per block. preactD via atomics (zeroed).
// ============================================================
__global__ __launch_bounds__(256) void routing_act_part(const float* __restrict__ x3m,
    const u16* __restrict__ dwb_a, const float* __restrict__ logits,
    float* __restrict__ preactD, int uniform)
{
    __shared__ float x3s[8192];    // [b][il][a] 32 KB
    __shared__ float rs[10240];    // [b][il][o] 40 KB
    const int c = blockIdx.x, bg = blockIdx.y;
    const int tid = threadIdx.x;
    for (int q = tid; q < 8192; q += 256) {
        const int b_l = q >> 10, rest = q & 1023, il = rest >> 3, a = rest & 7;
        const int i = c * 128 + il, cap = i / 36, p = i - cap * 36;
        x3s[q] = x3m[((size_t)(bg * 8 + b_l) * 36 + p) * 256 + cap * 8 + a];
    }
    if (!uniform && tid < 128) {
        const int i = c * 128 + tid;
        for (int b_l = 0; b_l < 8; ++b_l) {
            const float* lg = &logits[((size_t)(bg * 8 + b_l) * 1152 + i) * 10];
            float l[10]; float mx = -1e30f;
            #pragma unroll
            for (int k = 0; k < 10; ++k) { l[k] = lg[k]; mx = fmaxf(mx, l[k]); }
            float s = 0.f;
            #pragma unroll
            for (int k = 0; k < 10; ++k) { l[k] = __expf(l[k] - mx); s += l[k]; }
            const float inv = 1.f / s;
            #pragma unroll
            for (int k = 0; k < 10; ++k) rs[(b_l * 128 + tid) * 10 + k] = l[k] * inv;
        }
    }
    __syncthreads();
    if (tid < 160) {
        const int ot = tid;                       // o*16+t
        const int o = tid >> 4;
        float preg[8];
        #pragma unroll
        for (int b_l = 0; b_l < 8; ++b_l) preg[b_l] = 0.f;
        #pragma unroll 2
        for (int il = 0; il < 128; ++il) {
            const int i = c * 128 + il;
            const uint4 dq = *reinterpret_cast<const uint4*>(
                &dwb_a[((size_t)i * 160 + ot) * 8]);
            const u32 du[4] = {dq.x, dq.y, dq.z, dq.w};
            float dv[8];
            #pragma unroll
            for (int q = 0; q < 4; ++q) {
                dv[2 * q]     = __uint_as_float(du[q] << 16);
                dv[2 * q + 1] = __uint_as_float(du[q] & 0xffff0000u);
            }
            #pragma unroll
            for (int b_l = 0; b_l < 8; ++b_l) {
                const float* xp = &x3s[(b_l * 128 + il) * 8];
                float v = 0.f;
                #pragma unroll
                for (int a = 0; a < 8; ++a) v += xp[a] * dv[a];
                const float r = uniform ? 0.1f : rs[(b_l * 128 + il) * 10 + o];
                preg[b_l] += r * v;
            }
        }
        #pragma unroll
        for (int b_l = 0; b_l < 8; ++b_l)
            unsafeAtomicAdd(&preactD[(size_t)(bg * 8 + b_l) * 160 + tid], preg[b_l]);
    }
}

// ============================================================
// Kernel 7: preactD + digit_b -> squash -> act (+digit out)
// ============================================================
__global__ __launch_bounds__(192) void routing_squash(const float* __restrict__ preactD,
    const float* __restrict__ db, float* __restrict__ act, float* __restrict__ dout)
{
    const int b = blockIdx.x, tid = threadIdx.x;
    if (tid < 160) {
        float pre = preactD[(size_t)b * 160 + tid] + db[tid];
        float sq = pre * pre;
        sq += __shfl_xor(sq, 1); sq += __shfl_xor(sq, 2);
        sq += __shfl_xor(sq, 4); sq += __shfl_xor(sq, 8);
        float scale = (sq / (1.f + sq)) * rsqrtf(sq + 1e-9f);
        float a = pre * scale;
        act[(size_t)b * 160 + tid] = a;
        if (dout) dout[(size_t)b * 160 + tid] = a;
    }
}

// ============================================================
// Kernel 8: logits update (dwb_t [i][a][o][t], uint4 over t).
// grid (9, 32), block 256 = 128 i x 2 o-halves; 8 b's inside.
// ============================================================
__global__ __launch_bounds__(256) void routing_upd_part(const float* __restrict__ x3m,
    const u16* __restrict__ dwb_t, const float* __restrict__ act,
    float* __restrict__ logits, int first)
{
    __shared__ float x3s[8192];
    __shared__ float acts[1280];
    const int c = blockIdx.x, bg = blockIdx.y;
    const int tid = threadIdx.x;
    for (int q = tid; q < 8192; q += 256) {
        const int b_l = q >> 10, rest = q & 1023, il = rest >> 3, a = rest & 7;
        const int i = c * 128 + il, cap = i / 36, p = i - cap * 36;
        x3s[q] = x3m[((size_t)(bg * 8 + b_l) * 36 + p) * 256 + cap * 8 + a];
    }
    for (int q = tid; q < 1280; q += 256)
        acts[q] = act[(size_t)(bg * 8 + q / 160) * 160 + (q % 160)];
    __syncthreads();
    const int il = tid >> 1, half = tid & 1;
    const int i = c * 128 + il;
    #pragma unroll 1
    for (int oo = 0; oo < 5; ++oo) {
        const int o = half * 5 + oo;
        float s[8];
        #pragma unroll
        for (int b_l = 0; b_l < 8; ++b_l) s[b_l] = 0.f;
        #pragma unroll
        for (int a = 0; a < 8; ++a) {
            const uint4* dp = reinterpret_cast<const uint4*>(
                &dwb_t[(((size_t)i * 8 + a) * 10 + o) * 16]);
            uint4 d0 = dp[0], d1 = dp[1];
            const u32 du[8] = {d0.x, d0.y, d0.z, d0.w, d1.x, d1.y, d1.z, d1.w};
            #pragma unroll
            for (int b_l = 0; b_l < 8; ++b_l) {
                const float* ap = &acts[b_l * 160 + o * 16];
                float inner = 0.f;
                #pragma unroll
                for (int q = 0; q < 8; ++q) {
                    inner += __uint_as_float(du[q] << 16) * ap[2 * q];
                    inner += __uint_as_float(du[q] & 0xffff0000u) * ap[2 * q + 1];
                }
                s[b_l] += x3s[(b_l * 128 + il) * 8 + a] * inner;
            }
        }
        #pragma unroll
        for (int b_l = 0; b_l < 8; ++b_l) {
            float* lp = &logits[((size_t)(bg * 8 + b_l) * 1152 + i) * 10 + o];
            if (first) *lp = s[b_l]; else *lp += s[b_l];
        }
    }
}

// ============================================================
// Kernel 9: masked[b][j] = act[b][j] * y[b][j/16]
// ============================================================
__global__ __launch_bounds__(256) void masked_kernel(const float* __restrict__ act,
    const float* __restrict__ y, float* __restrict__ masked)
{
    const int gid = blockIdx.x * 256 + threadIdx.x;  // 40960
    const int b = gid / 160, j = gid % 160;
    masked[gid] = act[gid] * y[b * 10 + (j >> 4)];
}

// ============================================================
// Kernel 10: dense layer; 2 batch rows/block; mode 0=relu, 1=sigmoid
// grid (B/2, ceil(N/256)), block 256
// ============================================================
__global__ __launch_bounds__(256) void mlp_layer(const float* __restrict__ in,
    const float* __restrict__ w, const float* __restrict__ bias,
    float* __restrict__ outp, int K, int N, int mode)
{
    __shared__ float ins[2 * 1024];
    const int b0 = blockIdx.x * 2;
    const int n = blockIdx.y * 256 + threadIdx.x;
    for (int idx = threadIdx.x; idx < 2 * K; idx += 256)
        ins[idx] = in[(size_t)b0 * K + idx];
    __syncthreads();
    if (n < N) {
        float a0 = 0.f, a1 = 0.f;
        for (int k = 0; k < K; ++k) {
            const float wvv = w[(size_t)k * N + n];
            a0 += ins[k] * wvv;
            a1 += ins[K + k] * wvv;
        }
        const float bv = bias[n];
        float v[2] = {a0 + bv, a1 + bv};
        #pragma unroll
        for (int j = 0; j < 2; ++j) {
            float xv = v[j];
            xv = (mode == 0) ? fmaxf(xv, 0.f) : 1.f / (1.f + __expf(-xv));
            outp[(size_t)(b0 + j) * N + n] = xv;
        }
    }
}

// ============================================================
extern "C" void kernel_launch(void* const* d_in, const int* in_sizes, int n_in,
                              void* d_out, int out_size, void* d_ws, size_t ws_size,
                              hipStream_t stream) {
    const float* x   = (const float*)d_in[0];
    const float* y   = (const float*)d_in[1];
    const float* c1w = (const float*)d_in[2];
    const float* c1b = (const float*)d_in[3];
    const float* pw  = (const float*)d_in[4];
    const float* pb  = (const float*)d_in[5];
    const float* dw  = (const float*)d_in[6];
    const float* db  = (const float*)d_in[7];
    const float* w1  = (const float*)d_in[8];
    const float* b1  = (const float*)d_in[9];
    const float* w2  = (const float*)d_in[10];
    const float* b2  = (const float*)d_in[11];
    const float* w3  = (const float*)d_in[12];
    const float* b3  = (const float*)d_in[13];
    float* out = (float*)d_out;
    char* ws = (char*)d_ws;

    static const int exp_sizes[14] = {200704, 2560, 20736, 256, 5308416, 256,
                                      1474560, 160, 81920, 512, 524288, 1024,
                                      802816, 784};
    int bad = (n_in == 14) ? -1 : -2;
    if (bad == -1)
        for (int i = 0; i < 14; ++i) if (in_sizes[i] != exp_sizes[i]) { bad = i; break; }
    if (bad != -1) {
        fill_sentinel<<<(out_size + 255) / 256, 256, 0, stream>>>(out, out_size,
            7168.f + 16.f * (float)(bad + 1));
        return;
    }
    const size_t NEEDED = 72482816ULL;
    if (ws_size < NEEDED) {
        fill_sentinel<<<(out_size + 255) / 256, 256, 0, stream>>>(out, out_size, 111.0f);
        return;
    }

    // GEMM-phase live set: h + wT2 + x3m = 72.5 MB
    u16*   h       = (u16*)(ws);                    // [0, 52,428,800)
    u16*   wT2     = (u16*)(ws + 52428800);         // [52,428,800, 63,045,632)
    float* x3m     = (float*)(ws + 63045632);       // [63,045,632, 72,482,816)
    u16*   c1wb    = (u16*)(ws + 63045632);         // 41 KB inside x3m region (dead before memset)
    // after GEMM, h/wT2 dead: routing/recon overlays
    float* logits  = (float*)(ws);                  // 11,796,480
    float* act     = (float*)(ws + 11796480);       //    163,840
    float* masked  = (float*)(ws + 11960320);       //    163,840
    float* r1      = (float*)(ws + 12124160);       //    524,288
    float* r2      = (float*)(ws + 12648448);       //  1,048,576
    float* preactD = (float*)(ws + 13697024);       //    163,840
    u16*   dwb_t   = (u16*)(ws + 13860864);         //  2,949,120
    u16*   dwb_a   = (u16*)(ws + 16809984);         //  2,949,120 (ends 19.76 MB)

    conv_c1wb<<<81, 256, 0, stream>>>(c1w, c1wb);
    conv1_kernel<<<1024, 256, 0, stream>>>(x, c1wb, c1b, h);
    transpose_primw<<<256, 256, 0, stream>>>(pw, wT2);
    hipMemsetAsync(x3m, 0, 9437184, stream);        // also kills c1wb (dead)
    prim_gemm_split<<<dim3(144, 12), 256, 0, stream>>>(h, wT2, x3m);
    squash_kernel<<<9216, 256, 0, stream>>>(x3m, pb);
    conv_dwb<<<5760, 256, 0, stream>>>(dw, dwb_t, dwb_a);

    // routing iter 1 (uniform), 2, 3
    hipMemsetAsync(preactD, 0, 163840, stream);
    routing_act_part<<<dim3(9, 32), 256, 0, stream>>>(x3m, dwb_a, logits, preactD, 1);
    routing_squash<<<256, 192, 0, stream>>>(preactD, db, act, (float*)nullptr);
    routing_upd_part<<<dim3(9, 32), 256, 0, stream>>>(x3m, dwb_t, act, logits, 1);

    hipMemsetAsync(preactD, 0, 163840, stream);
    routing_act_part<<<dim3(9, 32), 256, 0, stream>>>(x3m, dwb_a, logits, preactD, 0);
    routing_squash<<<256, 192, 0, stream>>>(preactD, db, act, (float*)nullptr);
    routing_upd_part<<<dim3(9, 32), 256, 0, stream>>>(x3m, dwb_t, act, logits, 0);

    hipMemsetAsync(preactD, 0, 163840, stream);
    routing_act_part<<<dim3(9, 32), 256, 0, stream>>>(x3m, dwb_a, logits, preactD, 0);
    routing_squash<<<256, 192, 0, stream>>>(preactD, db, act, out);

    // reconstruction
    masked_kernel<<<160, 256, 0, stream>>>(act, y, masked);
    mlp_layer<<<dim3(128, 2), 256, 0, stream>>>(masked, w1, b1, r1, 160, 512, 0);
    mlp_layer<<<dim3(128, 4), 256, 0, stream>>>(r1, w2, b2, r2, 512, 1024, 0);
    mlp_layer<<<dim3(128, 4), 256, 0, stream>>>(r2, w3, b3, out + 40960, 1024, 784, 1);
}